// Round 1
// baseline (221.932 us; speedup 1.0000x reference)
//
#include <hip/hip_runtime.h>
#include <math.h>

#define DM 2048
#define NEXP 64
#define NTOK 16384
#define NSLICE 4
#define KSL (DM / NSLICE)     // 512 k per K-slice
#define KC 32                 // k per chunk == one MFMA k-step
#define NCH (KSL / KC)        // 16 chunks
#define MBLK 64               // tokens per block (4 M-tiles of 16, one per wave)
#define NBLK1 ((NTOK / MBLK) * NSLICE)  // 1024 blocks
#define NKG (DM / KC)                   // 64 global k-steps
#define WFRAG_BYTES (NKG * 12 * 1024)   // [kg][limb*4+nt][lane][16B] = 768 KB
#define PART_BYTES (NSLICE * NEXP * NTOK * 4)  // 16.8 MB, layout [s*64+e][t]

typedef __attribute__((ext_vector_type(8))) short short8;
typedef __attribute__((ext_vector_type(4))) short short4v;
typedef __attribute__((ext_vector_type(4))) float f32x4;

// Truncating 3-limb bf16 split: f = h+m+l, residual ~2^-24 rel.
__device__ __forceinline__ void split3t(float f, unsigned short& h,
                                        unsigned short& m, unsigned short& l) {
  unsigned u = __float_as_uint(f);
  h = (unsigned short)(u >> 16);
  float f1 = f - __uint_as_float(u & 0xFFFF0000u);
  unsigned u1 = __float_as_uint(f1);
  m = (unsigned short)(u1 >> 16);
  float f2 = f1 - __uint_as_float(u1 & 0xFFFF0000u);
  l = (unsigned short)(__float_as_uint(f2) >> 16);
}

__device__ __forceinline__ void split8(const f32x4& a0, const f32x4& a1,
                                       short8& h, short8& m, short8& l) {
  float v[8] = {a0[0], a0[1], a0[2], a0[3], a1[0], a1[1], a1[2], a1[3]};
#pragma unroll
  for (int j = 0; j < 8; ++j) {
    unsigned short hh, mm, ll;
    split3t(v[j], hh, mm, ll);
    h[j] = (short)hh; m[j] = (short)mm; l[j] = (short)ll;
  }
}

// Pre-split W into MFMA-B-fragment-ordered limb blocks (lane-indexed):
// wfrag[((kg*12 + limb*4 + nt)*64 + lane)*8 + j] =
//   limb of W[nt*16 + (lane&15)][kg*32 + (lane>>4)*8 + j]
__global__ void convw_kernel(const float* __restrict__ W,
                             unsigned short* __restrict__ wfrag) {
  const int kg = blockIdx.x;
  const int lane = threadIdx.x & 63;
  const int nt = threadIdx.x >> 6;
  const int e = nt * 16 + (lane & 15);
  const int kpos = kg * 32 + (lane >> 4) * 8;
  const f32x4* wp = (const f32x4*)(W + (size_t)e * DM + kpos);
  f32x4 w0 = wp[0], w1 = wp[1];
  short8 h, m, l;
  split8(w0, w1, h, m, l);
  size_t base = ((size_t)(kg * 12 + nt) * 64 + lane) * 8;
  *(short8*)(wfrag + base) = h;
  *(short8*)(wfrag + base + (size_t)4 * 64 * 8) = m;
  *(short8*)(wfrag + base + (size_t)8 * 64 * 8) = l;
}

// K1 (R7 rewrite): barrier-free, LDS-free, wave-independent.
// Wave w of block (tg,s) owns M-tile tok0+16w (16 tokens) x 64 experts x
// K-slice s. A-fragment loaded global->reg in MFMA layout (lane l holds
// row l&15, k = (l>>4)*8 + j), split to 3 bf16 limbs in-register; B limbs
// from L2-resident wfrag (identical addresses across the block's 4 waves
// -> L1 broadcast). A prefetched 2 chunks deep (64 B/lane in flight covers
// ~900cy HBM latency); B one nt-group deep. No syncs anywhere: waves
// destagger freely, so stalls overlap across the 16 waves/CU.
// Accumulation order (chunk order, 6-product order) is bitwise identical
// to the previous LDS version -> same numerics.
__global__ __launch_bounds__(256, 4)
void router_gemm(const float* __restrict__ x,
                 const unsigned short* __restrict__ wfrag,
                 float* __restrict__ part) {
  const int lane = threadIdx.x & 63;
  const int wv = threadIdx.x >> 6;
  const int col = lane & 15;
  const int quad = lane >> 4;
  const int tg = blockIdx.x >> 2;
  const int s = blockIdx.x & 3;
  const int tok0 = tg * MBLK;
  const int kg0 = s * NCH;

  // this lane's A pointer: token row (tok0 + wv*16 + col), k base
  // s*KSL + quad*8; chunk c adds c*KC.
  const float* xp =
      x + (size_t)(tok0 + wv * 16 + col) * DM + s * KSL + quad * 8;
  const unsigned short* bb = wfrag + (size_t)lane * 8;

  f32x4 acc[4];
#pragma unroll
  for (int nt = 0; nt < 4; ++nt) acc[nt] = (f32x4){0.f, 0.f, 0.f, 0.f};

  // A prefetch pipeline, 2 chunks deep (named regs, all indices static
  // after full unroll -> no scratch).
  f32x4 pa0 = ((const f32x4*)xp)[0];
  f32x4 pa1 = ((const f32x4*)xp)[1];
  f32x4 qa0 = ((const f32x4*)(xp + KC))[0];
  f32x4 qa1 = ((const f32x4*)(xp + KC))[1];

  // B prefetch, one nt-group (3 frags) deep.
  short8 Bh = *(const short8*)(bb + (size_t)(kg0 * 12 + 0) * 512);
  short8 Bm = *(const short8*)(bb + (size_t)(kg0 * 12 + 4) * 512);
  short8 Bl = *(const short8*)(bb + (size_t)(kg0 * 12 + 8) * 512);

#pragma unroll
  for (int c = 0; c < NCH; ++c) {
    const int kg = kg0 + c;
    short8 ah, am, al;
    split8(pa0, pa1, ah, am, al);
    pa0 = qa0; pa1 = qa1;
    if (c + 2 < NCH) {
      const float* xn = xp + (size_t)(c + 2) * KC;
      qa0 = ((const f32x4*)xn)[0];
      qa1 = ((const f32x4*)xn)[1];
    }
#pragma unroll
    for (int nt = 0; nt < 4; ++nt) {
      short8 bh = Bh, bm = Bm, bl = Bl;
      // prefetch next nt-group (or chunk c+1's group 0)
      const int nf = (nt < 3) ? (kg * 12 + nt + 1)
                              : ((c + 1 < NCH) ? (kg + 1) * 12 : -1);
      if (nf >= 0) {
        Bh = *(const short8*)(bb + (size_t)(nf + 0) * 512);
        Bm = *(const short8*)(bb + (size_t)(nf + 4) * 512);
        Bl = *(const short8*)(bb + (size_t)(nf + 8) * 512);
      }
      f32x4 cc = acc[nt];
      cc = __builtin_amdgcn_mfma_f32_16x16x32_bf16(ah, bh, cc, 0, 0, 0);
      cc = __builtin_amdgcn_mfma_f32_16x16x32_bf16(ah, bm, cc, 0, 0, 0);
      cc = __builtin_amdgcn_mfma_f32_16x16x32_bf16(am, bh, cc, 0, 0, 0);
      cc = __builtin_amdgcn_mfma_f32_16x16x32_bf16(ah, bl, cc, 0, 0, 0);
      cc = __builtin_amdgcn_mfma_f32_16x16x32_bf16(al, bh, cc, 0, 0, 0);
      cc = __builtin_amdgcn_mfma_f32_16x16x32_bf16(am, bm, cc, 0, 0, 0);
      acc[nt] = cc;
    }
  }

  // store partials [s*64+e][t]: e = nt*16+col, t = tok0 + wv*16 + quad*4 + r
#pragma unroll
  for (int nt = 0; nt < 4; ++nt) {
    const size_t e = (size_t)(s * NEXP + nt * 16 + col);
    *(f32x4*)(part + e * NTOK + tok0 + wv * 16 + quad * 4) = acc[nt];
  }
}

// K2: lane-per-token reduce + serial top-2 (verified R6, unchanged).
__global__ __launch_bounds__(256, 4)
void router_reduce(const float* __restrict__ part,
                   const float* __restrict__ bias, float* __restrict__ out) {
  const int lane = threadIdx.x & 63;
  const int wv = threadIdx.x >> 6;
  const int q = lane >> 4;
  const int t = blockIdx.x * 64 + wv * 16 + (lane & 15);

  float v1 = -INFINITY, v2 = -INFINITY;
  int i1 = 0, i2 = 0;
#pragma unroll
  for (int e = 0; e < NEXP; ++e) {
    float p = part[(size_t)(q * NEXP + e) * NTOK + t];
    p += __shfl_xor(p, 16, 64);
    p += __shfl_xor(p, 32, 64);
    const float v = p + bias[e];
    const bool a = v > v1;
    const bool b = v > v2;
    const float nv2 = a ? v1 : (b ? v : v2);
    const int ni2 = a ? i1 : (b ? e : i2);
    v2 = nv2; i2 = ni2;
    i1 = a ? e : i1;
    v1 = a ? v : v1;
  }
  if (q == 0) {
    const float ex = expf(v2 - v1);
    const float den = 1.f + ex;
    *(float2*)(out + 2 * t) = make_float2(1.f / den, ex / den);
    *(float2*)(out + 2 * NTOK + 2 * t) = make_float2((float)i1, (float)i2);
  }
}

// Fallback (ws too small): verified single-kernel path, inline W split.
__global__ __launch_bounds__(512, 2)
void router_fb(const float* __restrict__ x, const float* __restrict__ W,
               const float* __restrict__ bias, float* __restrict__ out) {
  const int lane = threadIdx.x & 63;
  const int wv = threadIdx.x >> 6;
  const int col = lane & 15;
  const int quad = lane >> 4;
  const int tok0 = blockIdx.x * 32;
  const int k0 = wv * 256;

  __shared__ float part[8][32][68];

  f32x4 acc[2][4];
#pragma unroll
  for (int ms = 0; ms < 2; ++ms)
#pragma unroll
    for (int nt = 0; nt < 4; ++nt) acc[ms][nt] = (f32x4){0.f, 0.f, 0.f, 0.f};

  for (int ks = 0; ks < 8; ++ks) {
    const int k = k0 + ks * 32 + quad * 8;
    short8 ah[2], am2[2], al2[2];
#pragma unroll
    for (int ms = 0; ms < 2; ++ms) {
      const f32x4* ap = (const f32x4*)(x + (size_t)(tok0 + ms * 16 + col) * DM + k);
      f32x4 a0 = ap[0], a1 = ap[1];
      split8(a0, a1, ah[ms], am2[ms], al2[ms]);
    }
#pragma unroll
    for (int nt = 0; nt < 4; ++nt) {
      short8 bh, bm, bl;
      const f32x4* wp = (const f32x4*)(W + (size_t)(nt * 16 + col) * DM + k);
      f32x4 w0 = wp[0], w1 = wp[1];
      split8(w0, w1, bh, bm, bl);
#pragma unroll
      for (int ms = 0; ms < 2; ++ms) {
        f32x4 cc = acc[ms][nt];
        cc = __builtin_amdgcn_mfma_f32_16x16x32_bf16(ah[ms], bh, cc, 0, 0, 0);
        cc = __builtin_amdgcn_mfma_f32_16x16x32_bf16(ah[ms], bm, cc, 0, 0, 0);
        cc = __builtin_amdgcn_mfma_f32_16x16x32_bf16(am2[ms], bh, cc, 0, 0, 0);
        cc = __builtin_amdgcn_mfma_f32_16x16x32_bf16(ah[ms], bl, cc, 0, 0, 0);
        cc = __builtin_amdgcn_mfma_f32_16x16x32_bf16(al2[ms], bh, cc, 0, 0, 0);
        cc = __builtin_amdgcn_mfma_f32_16x16x32_bf16(am2[ms], bm, cc, 0, 0, 0);
        acc[ms][nt] = cc;
      }
    }
  }
#pragma unroll
  for (int ms = 0; ms < 2; ++ms)
#pragma unroll
    for (int nt = 0; nt < 4; ++nt)
#pragma unroll
      for (int r = 0; r < 4; ++r)
        part[wv][ms * 16 + quad * 4 + r][nt * 16 + col] = acc[ms][nt][r];
  __syncthreads();
  const float bl_ = bias[lane];
#pragma unroll
  for (int ti = 0; ti < 4; ++ti) {
    const int t = wv * 4 + ti;
    float v1 = bl_;
#pragma unroll
    for (int p = 0; p < 8; ++p) v1 += part[p][t][lane];
    int i1 = lane;
    float v2 = -INFINITY;
    int i2 = NEXP;
#pragma unroll
    for (int off = 32; off > 0; off >>= 1) {
      float ov1 = __shfl_xor(v1, off, 64);
      int   oi1 = __shfl_xor(i1, off, 64);
      float ov2 = __shfl_xor(v2, off, 64);
      int   oi2 = __shfl_xor(i2, off, 64);
      bool afirst = (v1 > ov1) || (v1 == ov1 && i1 < oi1);
      float w1v = afirst ? v1 : ov1;  int w1i = afirst ? i1 : oi1;
      float c1v = afirst ? v2 : ov2;  int c1i = afirst ? i2 : oi2;
      float c2v = afirst ? ov1 : v1;  int c2i = afirst ? oi1 : i1;
      bool sfirst = (c1v > c2v) || (c1v == c2v && c1i < c2i);
      v1 = w1v; i1 = w1i;
      v2 = sfirst ? c1v : c2v;
      i2 = sfirst ? c1i : c2i;
    }
    if (lane == 0) {
      const float ex = expf(v2 - v1);
      const float den = 1.f + ex;
      const int token = tok0 + t;
      *(float2*)(out + 2 * token) = make_float2(1.f / den, ex / den);
      *(float2*)(out + 2 * NTOK + 2 * token) =
          make_float2((float)i1, (float)i2);
    }
  }
}

extern "C" void kernel_launch(void* const* d_in, const int* in_sizes, int n_in,
                              void* d_out, int out_size, void* d_ws, size_t ws_size,
                              hipStream_t stream) {
  const float* x = (const float*)d_in[0];
  const float* W = (const float*)d_in[1];
  const float* b = (const float*)d_in[2];
  float* out = (float*)d_out;

  const size_t need = (size_t)WFRAG_BYTES + (size_t)PART_BYTES; // ~17.6 MB
  if (ws_size >= need) {
    unsigned short* wfrag = (unsigned short*)d_ws;
    float* part = (float*)((char*)d_ws + WFRAG_BYTES);
    hipLaunchKernelGGL(convw_kernel, dim3(NKG), dim3(256), 0, stream, W, wfrag);
    hipLaunchKernelGGL(router_gemm, dim3(NBLK1), dim3(256), 0, stream,
                       x, wfrag, part);
    hipLaunchKernelGGL(router_reduce, dim3(NTOK / 64), dim3(256), 0, stream,
                       part, b, out);
  } else {
    hipLaunchKernelGGL(router_fb, dim3(NTOK / 32), dim3(512), 0, stream,
                       x, W, b, out);
  }
}

// Round 3
// 210.039 us; speedup vs baseline: 1.0566x; 1.0566x over previous
//
#include <hip/hip_runtime.h>
#include <math.h>

#define DM 2048
#define NEXP 64
#define NTOK 16384
#define KC 32                  // k per chunk == one MFMA k-step
#define KSL 512                // k per wave (one K-quarter)
#define NCH (KSL / KC)         // 16 chunks per wave
#define MBLK 32                // tokens per block (2 M-tiles of 16 per wave)
#define NBLK (NTOK / MBLK)     // 512 blocks
#define NKG (DM / KC)          // 64 global k-steps
#define WFRAG_BYTES (NKG * 12 * 1024)  // [kg][limb*4+nt][lane][16B] = 768 KB
#define QS 2120                // LDS partial q-stride in floats (32*66 + 8)

typedef __attribute__((ext_vector_type(8))) short short8;
typedef __attribute__((ext_vector_type(4))) short short4v;
typedef __attribute__((ext_vector_type(4))) float f32x4;

// Truncating 3-limb bf16 split: f = h+m+l, residual ~2^-24 rel.
__device__ __forceinline__ void split3t(float f, unsigned short& h,
                                        unsigned short& m, unsigned short& l) {
  unsigned u = __float_as_uint(f);
  h = (unsigned short)(u >> 16);
  float f1 = f - __uint_as_float(u & 0xFFFF0000u);
  unsigned u1 = __float_as_uint(f1);
  m = (unsigned short)(u1 >> 16);
  float f2 = f1 - __uint_as_float(u1 & 0xFFFF0000u);
  l = (unsigned short)(__float_as_uint(f2) >> 16);
}

__device__ __forceinline__ void split8(const f32x4& a0, const f32x4& a1,
                                       short8& h, short8& m, short8& l) {
  float v[8] = {a0[0], a0[1], a0[2], a0[3], a1[0], a1[1], a1[2], a1[3]};
#pragma unroll
  for (int j = 0; j < 8; ++j) {
    unsigned short hh, mm, ll;
    split3t(v[j], hh, mm, ll);
    h[j] = (short)hh; m[j] = (short)mm; l[j] = (short)ll;
  }
}

// Pre-split W into MFMA-B-fragment-ordered limb blocks (lane-indexed):
// wfrag[((kg*12 + limb*4 + nt)*64 + lane)*8 + j] =
//   limb of W[nt*16 + (lane&15)][kg*32 + (lane>>4)*8 + j]
__global__ void convw_kernel(const float* __restrict__ W,
                             unsigned short* __restrict__ wfrag) {
  const int kg = blockIdx.x;
  const int lane = threadIdx.x & 63;
  const int nt = threadIdx.x >> 6;
  const int e = nt * 16 + (lane & 15);
  const int kpos = kg * 32 + (lane >> 4) * 8;
  const f32x4* wp = (const f32x4*)(W + (size_t)e * DM + kpos);
  f32x4 w0 = wp[0], w1 = wp[1];
  short8 h, m, l;
  split8(w0, w1, h, m, l);
  size_t base = ((size_t)(kg * 12 + nt) * 64 + lane) * 8;
  *(short8*)(wfrag + base) = h;
  *(short8*)(wfrag + base + (size_t)4 * 64 * 8) = m;
  *(short8*)(wfrag + base + (size_t)8 * 64 * 8) = l;
}

// Fully fused router (R9 = R8 with B-prefetch index FIX): one kernel does
// GEMM + cross-K reduce + top-2.
// Grid 512 x 256. Block = 32 tokens; wave wv owns K-quarter wv (512 k,
// 16 chunks) for ALL 32 tokens x 64 experts -> acc[2 mt][4 nt].
// A: global->reg in MFMA fragment layout (lane l: token row l&15,
// k = (l>>4)*8+j), 2-chunk-deep named-reg prefetch. B: explicit-index
// prefetch (R7's verified nf = kg*12+nt+1 / (kg+1)*12 formula — the R8
// rolling pointer skipped the limb-slot gap at the WRONG nt and read
// m-limb blocks as h -> wrong logits). Last prefetch overruns wfrag by
// <=9 KB into ws slack (16 KB reserved).
// Epilogue: K-quarter partials exchanged via LDS (strides padded so both
// write and read are 2-way bank aliases = free), then the verified
// lane-per-token serial top-2 (q = K-quarter, xor16/xor32 sum) on waves
// 0-1. No partials in HBM, no third kernel.
// Numerics: chunk order, 6-product order, and cross-quarter shuffle-sum
// order are identical to the verified 3-kernel path.
__global__ __launch_bounds__(256, 2)
void router_fused(const float* __restrict__ x,
                  const unsigned short* __restrict__ wfrag,
                  const float* __restrict__ bias, float* __restrict__ out) {
  const int lane = threadIdx.x & 63;
  const int wv = threadIdx.x >> 6;   // K-quarter
  const int col = lane & 15;
  const int quad = lane >> 4;
  const int tok0 = blockIdx.x * MBLK;
  const int kg0 = wv * NCH;

  __shared__ float pl[4 * QS];  // ~33.9 KB

  // A pointers for the wave's two M-tiles.
  const float* xp0 = x + (size_t)(tok0 + col) * DM + wv * KSL + quad * 8;
  const float* xp1 = xp0 + (size_t)16 * DM;
  const unsigned short* bb = wfrag + (size_t)lane * 8;

  f32x4 acc[2][4];
#pragma unroll
  for (int mt = 0; mt < 2; ++mt)
#pragma unroll
    for (int nt = 0; nt < 4; ++nt) acc[mt][nt] = (f32x4){0.f, 0.f, 0.f, 0.f};

  // A prefetch pipeline: P = chunk c, Q = chunk c+1 (all names static).
  f32x4 P00 = ((const f32x4*)xp0)[0], P01 = ((const f32x4*)xp0)[1];
  f32x4 P10 = ((const f32x4*)xp1)[0], P11 = ((const f32x4*)xp1)[1];
  f32x4 Q00 = ((const f32x4*)(xp0 + KC))[0], Q01 = ((const f32x4*)(xp0 + KC))[1];
  f32x4 Q10 = ((const f32x4*)(xp1 + KC))[0], Q11 = ((const f32x4*)(xp1 + KC))[1];

  // B prefetch, one nt-group (3 limb frags: g, g+4, g+8) deep.
  short8 Bh = *(const short8*)(bb + (size_t)(kg0 * 12 + 0) * 512);
  short8 Bm = *(const short8*)(bb + (size_t)(kg0 * 12 + 4) * 512);
  short8 Bl = *(const short8*)(bb + (size_t)(kg0 * 12 + 8) * 512);

#pragma unroll 2
  for (int c = 0; c < NCH; ++c) {
    const int kg = kg0 + c;
    short8 ah0, am0, al0, ah1, am1, al1;
    split8(P00, P01, ah0, am0, al0);
    split8(P10, P11, ah1, am1, al1);
    P00 = Q00; P01 = Q01; P10 = Q10; P11 = Q11;
    if (c + 2 < NCH) {  // uniform branch; guards x OOB on last 2 chunks
      const float* n0 = xp0 + (size_t)(c + 2) * KC;
      const float* n1 = xp1 + (size_t)(c + 2) * KC;
      Q00 = ((const f32x4*)n0)[0]; Q01 = ((const f32x4*)n0)[1];
      Q10 = ((const f32x4*)n1)[0]; Q11 = ((const f32x4*)n1)[1];
    }
#pragma unroll
    for (int nt = 0; nt < 4; ++nt) {
      short8 bh = Bh, bm = Bm, bl = Bl;
      // next nt-group: within-kg neighbor, or next kg's group 0.
      // (Last overall prefetch overruns wfrag into ws slack; harmless.)
      const int nf = (nt < 3) ? (kg * 12 + nt + 1) : (kg + 1) * 12;
      Bh = *(const short8*)(bb + (size_t)(nf + 0) * 512);
      Bm = *(const short8*)(bb + (size_t)(nf + 4) * 512);
      Bl = *(const short8*)(bb + (size_t)(nf + 8) * 512);
      {
        f32x4 cc = acc[0][nt];
        cc = __builtin_amdgcn_mfma_f32_16x16x32_bf16(ah0, bh, cc, 0, 0, 0);
        cc = __builtin_amdgcn_mfma_f32_16x16x32_bf16(ah0, bm, cc, 0, 0, 0);
        cc = __builtin_amdgcn_mfma_f32_16x16x32_bf16(am0, bh, cc, 0, 0, 0);
        cc = __builtin_amdgcn_mfma_f32_16x16x32_bf16(ah0, bl, cc, 0, 0, 0);
        cc = __builtin_amdgcn_mfma_f32_16x16x32_bf16(al0, bh, cc, 0, 0, 0);
        cc = __builtin_amdgcn_mfma_f32_16x16x32_bf16(am0, bm, cc, 0, 0, 0);
        acc[0][nt] = cc;
      }
      {
        f32x4 cc = acc[1][nt];
        cc = __builtin_amdgcn_mfma_f32_16x16x32_bf16(ah1, bh, cc, 0, 0, 0);
        cc = __builtin_amdgcn_mfma_f32_16x16x32_bf16(ah1, bm, cc, 0, 0, 0);
        cc = __builtin_amdgcn_mfma_f32_16x16x32_bf16(am1, bh, cc, 0, 0, 0);
        cc = __builtin_amdgcn_mfma_f32_16x16x32_bf16(ah1, bl, cc, 0, 0, 0);
        cc = __builtin_amdgcn_mfma_f32_16x16x32_bf16(al1, bh, cc, 0, 0, 0);
        cc = __builtin_amdgcn_mfma_f32_16x16x32_bf16(am1, bm, cc, 0, 0, 0);
        acc[1][nt] = cc;
      }
    }
  }

  // ---- exchange K-quarter partials via LDS ----
  // pl[wv*QS + t_local*66 + e]; QS%32==8 and 66%32==2 keep both the
  // write pattern (col+8*quad) and read pattern (8q+2tt) at 2-way.
#pragma unroll
  for (int mt = 0; mt < 2; ++mt)
#pragma unroll
    for (int nt = 0; nt < 4; ++nt)
#pragma unroll
      for (int r = 0; r < 4; ++r)
        pl[wv * QS + (mt * 16 + quad * 4 + r) * 66 + nt * 16 + col] =
            acc[mt][nt][r];
  __syncthreads();

  // ---- top-2 (verified serial chain): waves 0-1, lane=(q, token16) ----
  if (wv < 2) {
    const int tt = lane & 15;
    const int q = lane >> 4;
    const int tl = wv * 16 + tt;  // local token 0..31
    float v1 = -INFINITY, v2 = -INFINITY;
    int i1 = 0, i2 = 0;
#pragma unroll
    for (int e = 0; e < NEXP; ++e) {
      float p = pl[q * QS + tl * 66 + e];
      p += __shfl_xor(p, 16, 64);
      p += __shfl_xor(p, 32, 64);
      const float v = p + bias[e];
      const bool a = v > v1;
      const bool b = v > v2;
      const float nv2 = a ? v1 : (b ? v : v2);
      const int ni2 = a ? i1 : (b ? e : i2);
      v2 = nv2; i2 = ni2;
      i1 = a ? e : i1;
      v1 = a ? v : v1;
    }
    if (q == 0) {
      const int t = tok0 + tl;
      const float ex = expf(v2 - v1);
      const float den = 1.f + ex;
      *(float2*)(out + 2 * t) = make_float2(1.f / den, ex / den);
      *(float2*)(out + 2 * NTOK + 2 * t) = make_float2((float)i1, (float)i2);
    }
  }
}

// Fallback (ws too small): verified single-kernel path, inline W split.
__global__ __launch_bounds__(512, 2)
void router_fb(const float* __restrict__ x, const float* __restrict__ W,
               const float* __restrict__ bias, float* __restrict__ out) {
  const int lane = threadIdx.x & 63;
  const int wv = threadIdx.x >> 6;
  const int col = lane & 15;
  const int quad = lane >> 4;
  const int tok0 = blockIdx.x * 32;
  const int k0 = wv * 256;

  __shared__ float part[8][32][68];

  f32x4 acc[2][4];
#pragma unroll
  for (int ms = 0; ms < 2; ++ms)
#pragma unroll
    for (int nt = 0; nt < 4; ++nt) acc[ms][nt] = (f32x4){0.f, 0.f, 0.f, 0.f};

  for (int ks = 0; ks < 8; ++ks) {
    const int k = k0 + ks * 32 + quad * 8;
    short8 ah[2], am2[2], al2[2];
#pragma unroll
    for (int ms = 0; ms < 2; ++ms) {
      const f32x4* ap = (const f32x4*)(x + (size_t)(tok0 + ms * 16 + col) * DM + k);
      f32x4 a0 = ap[0], a1 = ap[1];
      split8(a0, a1, ah[ms], am2[ms], al2[ms]);
    }
#pragma unroll
    for (int nt = 0; nt < 4; ++nt) {
      short8 bh, bm, bl;
      const f32x4* wp = (const f32x4*)(W + (size_t)(nt * 16 + col) * DM + k);
      f32x4 w0 = wp[0], w1 = wp[1];
      split8(w0, w1, bh, bm, bl);
#pragma unroll
      for (int ms = 0; ms < 2; ++ms) {
        f32x4 cc = acc[ms][nt];
        cc = __builtin_amdgcn_mfma_f32_16x16x32_bf16(ah[ms], bh, cc, 0, 0, 0);
        cc = __builtin_amdgcn_mfma_f32_16x16x32_bf16(ah[ms], bm, cc, 0, 0, 0);
        cc = __builtin_amdgcn_mfma_f32_16x16x32_bf16(am2[ms], bh, cc, 0, 0, 0);
        cc = __builtin_amdgcn_mfma_f32_16x16x32_bf16(ah[ms], bl, cc, 0, 0, 0);
        cc = __builtin_amdgcn_mfma_f32_16x16x32_bf16(al2[ms], bh, cc, 0, 0, 0);
        cc = __builtin_amdgcn_mfma_f32_16x16x32_bf16(am2[ms], bm, cc, 0, 0, 0);
        acc[ms][nt] = cc;
      }
    }
  }
#pragma unroll
  for (int ms = 0; ms < 2; ++ms)
#pragma unroll
    for (int nt = 0; nt < 4; ++nt)
#pragma unroll
      for (int r = 0; r < 4; ++r)
        part[wv][ms * 16 + quad * 4 + r][nt * 16 + col] = acc[ms][nt][r];
  __syncthreads();
  const float bl_ = bias[lane];
#pragma unroll
  for (int ti = 0; ti < 4; ++ti) {
    const int t = wv * 4 + ti;
    float v1 = bl_;
#pragma unroll
    for (int p = 0; p < 8; ++p) v1 += part[p][t][lane];
    int i1 = lane;
    float v2 = -INFINITY;
    int i2 = NEXP;
#pragma unroll
    for (int off = 32; off > 0; off >>= 1) {
      float ov1 = __shfl_xor(v1, off, 64);
      int   oi1 = __shfl_xor(i1, off, 64);
      float ov2 = __shfl_xor(v2, off, 64);
      int   oi2 = __shfl_xor(i2, off, 64);
      bool afirst = (v1 > ov1) || (v1 == ov1 && i1 < oi1);
      float w1v = afirst ? v1 : ov1;  int w1i = afirst ? i1 : oi1;
      float c1v = afirst ? v2 : ov2;  int c1i = afirst ? i2 : oi2;
      float c2v = afirst ? ov1 : v1;  int c2i = afirst ? oi1 : i1;
      bool sfirst = (c1v > c2v) || (c1v == c2v && c1i < c2i);
      v1 = w1v; i1 = w1i;
      v2 = sfirst ? c1v : c2v;
      i2 = sfirst ? c1i : c2i;
    }
    if (lane == 0) {
      const float ex = expf(v2 - v1);
      const float den = 1.f + ex;
      const int token = tok0 + t;
      *(float2*)(out + 2 * token) = make_float2(1.f / den, ex / den);
      *(float2*)(out + 2 * NTOK + 2 * token) =
          make_float2((float)i1, (float)i2);
    }
  }
}

extern "C" void kernel_launch(void* const* d_in, const int* in_sizes, int n_in,
                              void* d_out, int out_size, void* d_ws, size_t ws_size,
                              hipStream_t stream) {
  const float* x = (const float*)d_in[0];
  const float* W = (const float*)d_in[1];
  const float* b = (const float*)d_in[2];
  float* out = (float*)d_out;

  // wfrag + 16 KB slack for the last B-prefetch overrun.
  const size_t need = (size_t)WFRAG_BYTES + 16384;
  if (ws_size >= need) {
    unsigned short* wfrag = (unsigned short*)d_ws;
    hipLaunchKernelGGL(convw_kernel, dim3(NKG), dim3(256), 0, stream, W, wfrag);
    hipLaunchKernelGGL(router_fused, dim3(NBLK), dim3(256), 0, stream,
                       x, wfrag, b, out);
  } else {
    hipLaunchKernelGGL(router_fb, dim3(NTOK / 32), dim3(512), 0, stream,
                       x, W, b, out);
  }
}